// Round 4
// baseline (25456.168 us; speedup 1.0000x reference)
//
#include <hip/hip_runtime.h>

typedef _Float16 half2_t __attribute__((ext_vector_type(2)));
typedef unsigned int uint32;

__device__ __forceinline__ float sigm(float v) { return 1.0f / (1.0f + __expf(-v)); }

// ---------------- pack W_hh: f32 -> f16 pairs (RTE), flat ----------------
__global__ __launch_bounds__(256) void pack_whh(const float* __restrict__ whh, uint32* __restrict__ whhd) {
  int p = blockIdx.x * 256 + threadIdx.x;   // exactly 524288 threads = 4*1024*256/2 pairs
  half2_t h;
  h[0] = (_Float16)whh[2 * p];
  h[1] = (_Float16)whh[2 * p + 1];
  whhd[p] = __builtin_bit_cast(uint32, h);
}

// ---------------- phase 1: xg = x[:, :, sk:sk+512] @ W_ih^T + bias, all f32 VALU ----------------
// chunk CT=32: rows R in [0,2048): b = R>>5, ct = R&31.  N = 1024 gates, K = 512.
// grid 2048 = 4(kb) x 32(rt) x 16(gt); block 256 = 16(tr) x 16(tc); 4x4 outputs/thread.
__global__ __launch_bounds__(256) void xgemm_f32(const float* __restrict__ x,
                                                 const float* __restrict__ wih,
                                                 const float* __restrict__ bih,
                                                 const float* __restrict__ bhh,
                                                 float* __restrict__ xg, int t0) {
  __shared__ float As[1040], Bs[1040];   // [16 k][65 pad-stride] each
  const int tid = threadIdx.x;
  const int bid = blockIdx.x;
  const int gt = bid & 15, rt = (bid >> 4) & 31, kb = bid >> 9;
  const int tr = tid & 15, tc = tid >> 4;
  const int sk = (kb * 1024) / 6;        // slice starts 0,170,341,512
  const int r_s = tid >> 4, k_s = tid & 15;

  float acc[4][4] = {};

  for (int K0 = 0; K0 < 512; K0 += 16) {
#pragma unroll
    for (int q = 0; q < 4; ++q) {
      int r = q * 16 + r_s;
      int R = rt * 64 + r;
      int b = R >> 5, ct = R & 31;
      As[k_s * 65 + r] = x[((size_t)(t0 + ct) * 64 + b) * 1024 + sk + K0 + k_s];
      int g = gt * 64 + r;
      Bs[k_s * 65 + r] = wih[((size_t)(kb * 1024) + g) * 512 + K0 + k_s];
    }
    __syncthreads();
#pragma unroll
    for (int kk = 0; kk < 16; ++kk) {
      float a[4], bb[4];
#pragma unroll
      for (int m = 0; m < 4; ++m) a[m] = As[kk * 65 + tr * 4 + m];
#pragma unroll
      for (int n = 0; n < 4; ++n) bb[n] = Bs[kk * 65 + tc * 4 + n];
#pragma unroll
      for (int m = 0; m < 4; ++m)
#pragma unroll
        for (int n = 0; n < 4; ++n) acc[m][n] += a[m] * bb[n];
    }
    __syncthreads();
  }
#pragma unroll
  for (int n = 0; n < 4; ++n) {
    int g = gt * 64 + tc * 4 + n;
    float bias = bih[kb * 1024 + g] + bhh[kb * 1024 + g];
#pragma unroll
    for (int m = 0; m < 4; ++m) {
      int R = rt * 64 + tr * 4 + m;
      int b = R >> 5, ct = R & 31;
      xg[((size_t)(kb * 64 + b) * 32 + ct) * 1024 + g] = acc[m][n] + bias;
    }
  }
}

// ---------------- phase 2: 256 independent chains, 1 block per (k,b), CT=32 steps ----------------
// 512 threads; thread j owns gate rows j and 512+j of the 1024-row W_hh[k].
// w0 (row j): 128 f16-pair dwords in VGPR. w1 (row 512+j): 64 dw VGPR + 64 dw LDS at wl[p2*512+j]
// (lane-consecutive -> conflict-free scalar reads). h kept as f16 pairs in hl (broadcast reads).
// All MAC accumulation in f32.
__global__ __launch_bounds__(512, 2) void lstm32(const float* __restrict__ xg,
                                                 const uint32* __restrict__ whh16,
                                                 const float* __restrict__ h0,
                                                 const float* __restrict__ c0,
                                                 float* __restrict__ out,
                                                 float* __restrict__ state, int t0, int last) {
  extern __shared__ uint32 lds[];
  uint32* wl = lds;                     // [64][512] dw = 32768 dw
  uint32* hl = lds + 32768;             // 128 dw = 256 f16
  float*  gl = (float*)(lds + 32896);   // 1024 f32
  const int j = threadIdx.x;
  const int k = blockIdx.x >> 6, b = blockIdx.x & 63;

  const uint32* w0p = whh16 + ((size_t)(k * 1024 + j) << 7);
  const uint32* w1p = whh16 + ((size_t)(k * 1024 + 512 + j) << 7);
  uint32 w0[128], w1[64];
#pragma unroll
  for (int p = 0; p < 128; ++p) w0[p] = w0p[p];
#pragma unroll
  for (int p = 0; p < 64; ++p) w1[p] = w1p[p];
#pragma unroll
  for (int p = 0; p < 64; ++p) wl[p * 512 + j] = w1p[64 + p];

  float cst = 0.f, hlast = 0.f;
  if (j < 256) {
    int gi = b * 1024 + k * 256 + j;
    int si = (k * 64 + b) * 256 + j;
    float hv, cv;
    if (t0 == 0) { hv = h0[gi]; cv = c0[gi]; }
    else         { hv = state[si]; cv = state[65536 + si]; }
    cst = cv; hlast = hv;
    ((_Float16*)hl)[j] = (_Float16)hv;
  }
  __syncthreads();

  const float* xgp = xg + (size_t)(k * 64 + b) * 32768;   // 32 steps * 1024 gates
  float xa = xgp[j], xb2 = xgp[512 + j];
#pragma unroll 1
  for (int ct = 0; ct < 32; ++ct) {
    float g0 = xa, g1 = xb2;
    if (ct < 31) { xa = xgp[(ct + 1) * 1024 + j]; xb2 = xgp[(ct + 1) * 1024 + 512 + j]; }

    float s0 = 0.f, s1 = 0.f;
#pragma unroll
    for (int p = 0; p < 64; ++p) {   // h pairs 0..63: both rows' weights from VGPR
      half2_t hh = __builtin_bit_cast(half2_t, hl[p]);
      float ha = (float)hh[0], hb = (float)hh[1];
      half2_t w = __builtin_bit_cast(half2_t, w0[p]);
      s0 += (float)w[0] * ha + (float)w[1] * hb;
      w = __builtin_bit_cast(half2_t, w1[p]);
      s1 += (float)w[0] * ha + (float)w[1] * hb;
    }
#pragma unroll
    for (int p = 64; p < 128; ++p) {  // h pairs 64..127: row1 weights from LDS
      half2_t hh = __builtin_bit_cast(half2_t, hl[p]);
      float ha = (float)hh[0], hb = (float)hh[1];
      half2_t w = __builtin_bit_cast(half2_t, w0[p]);
      s0 += (float)w[0] * ha + (float)w[1] * hb;
      w = __builtin_bit_cast(half2_t, wl[(p - 64) * 512 + j]);
      s1 += (float)w[0] * ha + (float)w[1] * hb;
    }
    gl[j] = g0 + s0;
    gl[512 + j] = g1 + s1;
    __syncthreads();
    if (j < 256) {
      float iv = gl[j], fv = gl[256 + j], gv = gl[512 + j], ov = gl[768 + j];
      float cn = sigm(fv) * cst + sigm(iv) * tanhf(gv);
      float hn = sigm(ov) * tanhf(cn);
      cst = cn; hlast = hn;
      out[((size_t)(t0 + ct) * 64 + b) * 1024 + k * 256 + j] = hn;
      ((_Float16*)hl)[j] = (_Float16)hn;
    }
    __syncthreads();
  }
  if (j < 256) {
    int si = (k * 64 + b) * 256 + j;
    state[si] = hlast;
    state[65536 + si] = cst;
    if (last) {
      int gi = b * 1024 + k * 256 + j;
      out[33554432 + gi] = hlast;            // new_h
      out[33554432 + 65536 + gi] = cst;      // new_c
    }
  }
}

extern "C" void kernel_launch(void* const* d_in, const int* in_sizes, int n_in,
                              void* d_out, int out_size, void* d_ws, size_t ws_size,
                              hipStream_t stream) {
  const float* x   = (const float*)d_in[0];
  const float* h0  = (const float*)d_in[1];
  const float* c0  = (const float*)d_in[2];
  const float* Wih = (const float*)d_in[3];
  const float* Whh = (const float*)d_in[4];
  const float* bih = (const float*)d_in[5];
  const float* bhh = (const float*)d_in[6];
  float* out = (float*)d_out;
  char* ws = (char*)d_ws;

  // total ws usage: 36,175,872 B
  float*  xg    = (float*)ws;                   // 4*64*32*1024 f32 = 33,554,432 B
  uint32* whh16 = (uint32*)(ws + 33554432L);    //  2,097,152 B (f16 pairs)
  float*  state = (float*)(ws + 35651584L);     //    524,288 B

  hipFuncSetAttribute((const void*)lstm32, hipFuncAttributeMaxDynamicSharedMemorySize, 135680);

  pack_whh<<<2048, 256, 0, stream>>>(Whh, whh16);
  for (int c = 0; c < 16; ++c) {
    int t0 = c * 32;
    xgemm_f32<<<2048, 256, 0, stream>>>(x, Wih, bih, bhh, xg, t0);
    lstm32<<<256, 512, 135680, stream>>>(xg, whh16, h0, c0, out, state, t0, (c == 15) ? 1 : 0);
  }
}

// Round 5
// 25432.886 us; speedup vs baseline: 1.0009x; 1.0009x over previous
//
#include <hip/hip_runtime.h>

typedef _Float16 half2_t __attribute__((ext_vector_type(2)));
typedef unsigned int uintx4 __attribute__((ext_vector_type(4)));
typedef unsigned int uint32;

__device__ __forceinline__ float sigm(float v) { return 1.0f / (1.0f + __expf(-v)); }

// ---------------- pack W_hh: f32 -> f16 pairs (RTE), flat ----------------
__global__ __launch_bounds__(256) void pack_whh(const float* __restrict__ whh, uint32* __restrict__ whhd) {
  int p = blockIdx.x * 256 + threadIdx.x;   // exactly 524288 threads = 4*1024*256/2 pairs
  half2_t h;
  h[0] = (_Float16)whh[2 * p];
  h[1] = (_Float16)whh[2 * p + 1];
  whhd[p] = __builtin_bit_cast(uint32, h);
}

// ---------------- phase 1: xg = x[:, :, sk:sk+512] @ W_ih^T + bias, all f32 VALU ----------------
// chunk CT=32: rows R in [0,2048): b = R>>5, ct = R&31.  N = 1024 gates, K = 512.
// grid 2048 = 4(kb) x 32(rt) x 16(gt); block 256 = 16(tr) x 16(tc); 4x4 outputs/thread.
__global__ __launch_bounds__(256) void xgemm_f32(const float* __restrict__ x,
                                                 const float* __restrict__ wih,
                                                 const float* __restrict__ bih,
                                                 const float* __restrict__ bhh,
                                                 float* __restrict__ xg, int t0) {
  __shared__ float As[1040], Bs[1040];   // [16 k][65 pad-stride] each
  const int tid = threadIdx.x;
  const int bid = blockIdx.x;
  const int gt = bid & 15, rt = (bid >> 4) & 31, kb = bid >> 9;
  const int tr = tid & 15, tc = tid >> 4;
  const int sk = (kb * 1024) / 6;        // slice starts 0,170,341,512
  const int r_s = tid >> 4, k_s = tid & 15;

  float acc[4][4] = {};

  for (int K0 = 0; K0 < 512; K0 += 16) {
#pragma unroll
    for (int q = 0; q < 4; ++q) {
      int r = q * 16 + r_s;
      int R = rt * 64 + r;
      int b = R >> 5, ct = R & 31;
      As[k_s * 65 + r] = x[((size_t)(t0 + ct) * 64 + b) * 1024 + sk + K0 + k_s];
      int g = gt * 64 + r;
      Bs[k_s * 65 + r] = wih[((size_t)(kb * 1024) + g) * 512 + K0 + k_s];
    }
    __syncthreads();
#pragma unroll
    for (int kk = 0; kk < 16; ++kk) {
      float a[4], bb[4];
#pragma unroll
      for (int m = 0; m < 4; ++m) a[m] = As[kk * 65 + tr * 4 + m];
#pragma unroll
      for (int n = 0; n < 4; ++n) bb[n] = Bs[kk * 65 + tc * 4 + n];
#pragma unroll
      for (int m = 0; m < 4; ++m)
#pragma unroll
        for (int n = 0; n < 4; ++n) acc[m][n] += a[m] * bb[n];
    }
    __syncthreads();
  }
#pragma unroll
  for (int n = 0; n < 4; ++n) {
    int g = gt * 64 + tc * 4 + n;
    float bias = bih[kb * 1024 + g] + bhh[kb * 1024 + g];
#pragma unroll
    for (int m = 0; m < 4; ++m) {
      int R = rt * 64 + tr * 4 + m;
      int b = R >> 5, ct = R & 31;
      xg[((size_t)(kb * 64 + b) * 32 + ct) * 1024 + g] = acc[m][n] + bias;
    }
  }
}

// ---------------- phase 2: 256 independent chains, 1 block per (k,b), CT=32 steps ----------------
// 512 threads; thread j owns gate rows j and 512+j of the 1024-row W_hh[k].
// w0 (row j): 128 f16-pair dwords in VGPR. w1 (row 512+j): 64 dw VGPR + 64 dw LDS at wl[p2*512+j].
// launch_bounds(512,1): 512-VGPR budget so the ~250 live regs do NOT spill (round-4 spilled at the
// 256 cap -> 1.5 GB scratch traffic/dispatch). 135 KB LDS forces 1 block/CU anyway.
__global__ __launch_bounds__(512, 1) void lstm32(const float* __restrict__ xg,
                                                 const uint32* __restrict__ whh16,
                                                 const float* __restrict__ h0,
                                                 const float* __restrict__ c0,
                                                 float* __restrict__ out,
                                                 float* __restrict__ state, int t0, int last) {
  extern __shared__ uint32 lds[];
  uint32* wl = lds;                     // [64][512] dw = 32768 dw
  uint32* hl = lds + 32768;             // 128 dw = 256 f16
  float*  gl = (float*)(lds + 32896);   // 1024 f32
  const int j = threadIdx.x;
  const int k = blockIdx.x >> 6, b = blockIdx.x & 63;

  const uint32* w0p = whh16 + ((size_t)(k * 1024 + j) << 7);
  const uint32* w1p = whh16 + ((size_t)(k * 1024 + 512 + j) << 7);
  uint32 w0[128], w1[64];
#pragma unroll
  for (int q = 0; q < 32; ++q) *(uintx4*)&w0[q * 4] = *(const uintx4*)(w0p + q * 4);
#pragma unroll
  for (int q = 0; q < 16; ++q) *(uintx4*)&w1[q * 4] = *(const uintx4*)(w1p + q * 4);
#pragma unroll
  for (int q = 0; q < 16; ++q) {
    uintx4 v = *(const uintx4*)(w1p + 64 + q * 4);
#pragma unroll
    for (int e = 0; e < 4; ++e) wl[(q * 4 + e) * 512 + j] = v[e];
  }

  float cst = 0.f, hlast = 0.f;
  if (j < 256) {
    int gi = b * 1024 + k * 256 + j;
    int si = (k * 64 + b) * 256 + j;
    float hv, cv;
    if (t0 == 0) { hv = h0[gi]; cv = c0[gi]; }
    else         { hv = state[si]; cv = state[65536 + si]; }
    cst = cv; hlast = hv;
    ((_Float16*)hl)[j] = (_Float16)hv;
  }
  __syncthreads();

  const float* xgp = xg + (size_t)(k * 64 + b) * 32768;   // 32 steps * 1024 gates
  float xa = xgp[j], xb2 = xgp[512 + j];
#pragma unroll 1
  for (int ct = 0; ct < 32; ++ct) {
    float g0 = xa, g1 = xb2;
    if (ct < 31) { xa = xgp[(ct + 1) * 1024 + j]; xb2 = xgp[(ct + 1) * 1024 + 512 + j]; }

    float s0 = 0.f, s1 = 0.f;
#pragma unroll
    for (int p = 0; p < 64; ++p) {   // h pairs 0..63: both rows' weights from VGPR
      half2_t hh = __builtin_bit_cast(half2_t, hl[p]);
      float ha = (float)hh[0], hb = (float)hh[1];
      half2_t w = __builtin_bit_cast(half2_t, w0[p]);
      s0 += (float)w[0] * ha + (float)w[1] * hb;
      w = __builtin_bit_cast(half2_t, w1[p]);
      s1 += (float)w[0] * ha + (float)w[1] * hb;
    }
#pragma unroll
    for (int p = 64; p < 128; ++p) {  // h pairs 64..127: row1 weights from LDS
      half2_t hh = __builtin_bit_cast(half2_t, hl[p]);
      float ha = (float)hh[0], hb = (float)hh[1];
      half2_t w = __builtin_bit_cast(half2_t, w0[p]);
      s0 += (float)w[0] * ha + (float)w[1] * hb;
      w = __builtin_bit_cast(half2_t, wl[(p - 64) * 512 + j]);
      s1 += (float)w[0] * ha + (float)w[1] * hb;
    }
    gl[j] = g0 + s0;
    gl[512 + j] = g1 + s1;
    __syncthreads();
    if (j < 256) {
      float iv = gl[j], fv = gl[256 + j], gv = gl[512 + j], ov = gl[768 + j];
      float cn = sigm(fv) * cst + sigm(iv) * tanhf(gv);
      float hn = sigm(ov) * tanhf(cn);
      cst = cn; hlast = hn;
      out[((size_t)(t0 + ct) * 64 + b) * 1024 + k * 256 + j] = hn;
      ((_Float16*)hl)[j] = (_Float16)hn;
    }
    __syncthreads();
  }
  if (j < 256) {
    int si = (k * 64 + b) * 256 + j;
    state[si] = hlast;
    state[65536 + si] = cst;
    if (last) {
      int gi = b * 1024 + k * 256 + j;
      out[33554432 + gi] = hlast;            // new_h
      out[33554432 + 65536 + gi] = cst;      // new_c
    }
  }
}

extern "C" void kernel_launch(void* const* d_in, const int* in_sizes, int n_in,
                              void* d_out, int out_size, void* d_ws, size_t ws_size,
                              hipStream_t stream) {
  const float* x   = (const float*)d_in[0];
  const float* h0  = (const float*)d_in[1];
  const float* c0  = (const float*)d_in[2];
  const float* Wih = (const float*)d_in[3];
  const float* Whh = (const float*)d_in[4];
  const float* bih = (const float*)d_in[5];
  const float* bhh = (const float*)d_in[6];
  float* out = (float*)d_out;
  char* ws = (char*)d_ws;

  // total ws usage: 36,175,872 B
  float*  xg    = (float*)ws;                   // 4*64*32*1024 f32 = 33,554,432 B
  uint32* whh16 = (uint32*)(ws + 33554432L);    //  2,097,152 B (f16 pairs)
  float*  state = (float*)(ws + 35651584L);     //    524,288 B

  hipFuncSetAttribute((const void*)lstm32, hipFuncAttributeMaxDynamicSharedMemorySize, 135680);

  pack_whh<<<2048, 256, 0, stream>>>(Whh, whh16);
  for (int c = 0; c < 16; ++c) {
    int t0 = c * 32;
    xgemm_f32<<<2048, 256, 0, stream>>>(x, Wih, bih, bhh, xg, t0);
    lstm32<<<256, 512, 135680, stream>>>(xg, whh16, h0, c0, out, state, t0, (c == 15) ? 1 : 0);
  }
}

// Round 6
// 3755.360 us; speedup vs baseline: 6.7786x; 6.7724x over previous
//
#include <hip/hip_runtime.h>

typedef _Float16 half2_t __attribute__((ext_vector_type(2)));
typedef unsigned int uintx4 __attribute__((ext_vector_type(4)));
typedef unsigned int uint32;

__device__ __forceinline__ float sigm(float v) { return 1.0f / (1.0f + __expf(-v)); }

__device__ __forceinline__ float fdot2h(uint32 w, uint32 h, float c) {
#if __has_builtin(__builtin_amdgcn_fdot2)
  return __builtin_amdgcn_fdot2(__builtin_bit_cast(half2_t, w), __builtin_bit_cast(half2_t, h), c, false);
#else
  half2_t a = __builtin_bit_cast(half2_t, w), b = __builtin_bit_cast(half2_t, h);
  return c + (float)a[0] * (float)b[0] + (float)a[1] * (float)b[1];
#endif
}

// ---------------- pack W_hh: f32 -> f16 pairs (RTE), flat ----------------
__global__ __launch_bounds__(256) void pack_whh(const float* __restrict__ whh, uint32* __restrict__ whhd) {
  int p = blockIdx.x * 256 + threadIdx.x;   // 524288 threads = 4*1024*256/2 pairs
  half2_t h;
  h[0] = (_Float16)whh[2 * p];
  h[1] = (_Float16)whh[2 * p + 1];
  whhd[p] = __builtin_bit_cast(uint32, h);
}

// ---------------- phase 1: xg = x[:, :, sk:sk+512] @ W_ih^T + bias, f32 VALU ----------------
__global__ __launch_bounds__(256) void xgemm_f32(const float* __restrict__ x,
                                                 const float* __restrict__ wih,
                                                 const float* __restrict__ bih,
                                                 const float* __restrict__ bhh,
                                                 float* __restrict__ xg, int t0) {
  __shared__ float As[1040], Bs[1040];   // [16 k][65 pad-stride] each
  const int tid = threadIdx.x;
  const int bid = blockIdx.x;
  const int gt = bid & 15, rt = (bid >> 4) & 31, kb = bid >> 9;
  const int tr = tid & 15, tc = tid >> 4;
  const int sk = (kb * 1024) / 6;        // slice starts 0,170,341,512
  const int r_s = tid >> 4, k_s = tid & 15;

  float acc[4][4] = {};

  for (int K0 = 0; K0 < 512; K0 += 16) {
#pragma unroll
    for (int q = 0; q < 4; ++q) {
      int r = q * 16 + r_s;
      int R = rt * 64 + r;
      int b = R >> 5, ct = R & 31;
      As[k_s * 65 + r] = x[((size_t)(t0 + ct) * 64 + b) * 1024 + sk + K0 + k_s];
      int g = gt * 64 + r;
      Bs[k_s * 65 + r] = wih[((size_t)(kb * 1024) + g) * 512 + K0 + k_s];
    }
    __syncthreads();
#pragma unroll
    for (int kk = 0; kk < 16; ++kk) {
      float a[4], bb[4];
#pragma unroll
      for (int m = 0; m < 4; ++m) a[m] = As[kk * 65 + tr * 4 + m];
#pragma unroll
      for (int n = 0; n < 4; ++n) bb[n] = Bs[kk * 65 + tc * 4 + n];
#pragma unroll
      for (int m = 0; m < 4; ++m)
#pragma unroll
        for (int n = 0; n < 4; ++n) acc[m][n] += a[m] * bb[n];
    }
    __syncthreads();
  }
#pragma unroll
  for (int n = 0; n < 4; ++n) {
    int g = gt * 64 + tc * 4 + n;
    float bias = bih[kb * 1024 + g] + bhh[kb * 1024 + g];
#pragma unroll
    for (int m = 0; m < 4; ++m) {
      int R = rt * 64 + tr * 4 + m;
      int b = R >> 5, ct = R & 31;
      xg[((size_t)(kb * 64 + b) * 32 + ct) * 1024 + g] = acc[m][n] + bias;
    }
  }
}

// ---------------- phase 2: 256 independent chains, 1 block/(k,b), CT=32 steps ----------------
// 512 threads; thread j owns gate rows j and 512+j. Weights per thread = 64 half2-quads:
// row j -> W0..W31 (VGPR), row 512+j -> W32..W45 (VGPR, h-quads 0..13) + wl4 LDS (h-quads 14..31).
// All weights are NAMED uintx4 SSA values (never address-taken) so SROA/scratch cannot apply.
// LDS: hl (h as f16 pairs, 512 B) | gl (1024 f32) | wl4 (18*512 quads = 144 KB). Total 152064 B.
__global__ __launch_bounds__(512, 2) void lstm32(const float* __restrict__ xg,
                                                 const uint32* __restrict__ whh16,
                                                 const float* __restrict__ h0,
                                                 const float* __restrict__ c0,
                                                 float* __restrict__ out,
                                                 float* __restrict__ state, int t0, int last) {
  extern __shared__ uint32 lds[];
  const uintx4* hl4 = (const uintx4*)lds;       // 32 quads = 128 dw (h pairs)
  float*  gl  = (float*)(lds + 128);            // 1024 f32
  uintx4* wl4 = (uintx4*)(lds + 1152);          // 18*512 quads
  const int j = threadIdx.x;
  const int k = blockIdx.x >> 6, b = blockIdx.x & 63;

  const uintx4* w0q = (const uintx4*)(whh16 + ((size_t)(k * 1024 + j) << 7));
  const uintx4* w1q = (const uintx4*)(whh16 + ((size_t)(k * 1024 + 512 + j) << 7));
  uintx4 W0  = w0q[0],  W1  = w0q[1],  W2  = w0q[2],  W3  = w0q[3];
  uintx4 W4  = w0q[4],  W5  = w0q[5],  W6  = w0q[6],  W7  = w0q[7];
  uintx4 W8  = w0q[8],  W9  = w0q[9],  W10 = w0q[10], W11 = w0q[11];
  uintx4 W12 = w0q[12], W13 = w0q[13], W14 = w0q[14], W15 = w0q[15];
  uintx4 W16 = w0q[16], W17 = w0q[17], W18 = w0q[18], W19 = w0q[19];
  uintx4 W20 = w0q[20], W21 = w0q[21], W22 = w0q[22], W23 = w0q[23];
  uintx4 W24 = w0q[24], W25 = w0q[25], W26 = w0q[26], W27 = w0q[27];
  uintx4 W28 = w0q[28], W29 = w0q[29], W30 = w0q[30], W31 = w0q[31];
  uintx4 W32 = w1q[0],  W33 = w1q[1],  W34 = w1q[2],  W35 = w1q[3];
  uintx4 W36 = w1q[4],  W37 = w1q[5],  W38 = w1q[6],  W39 = w1q[7];
  uintx4 W40 = w1q[8],  W41 = w1q[9],  W42 = w1q[10], W43 = w1q[11];
  uintx4 W44 = w1q[12], W45 = w1q[13];
#pragma unroll
  for (int q = 14; q < 32; ++q) wl4[(q - 14) * 512 + j] = w1q[q];

  float cst = 0.f, hlast = 0.f;
  if (j < 256) {
    int gi = b * 1024 + k * 256 + j;
    int si = (k * 64 + b) * 256 + j;
    float hv, cv;
    if (t0 == 0) { hv = h0[gi]; cv = c0[gi]; }
    else         { hv = state[si]; cv = state[65536 + si]; }
    cst = cv; hlast = hv;
    ((_Float16*)lds)[j] = (_Float16)hv;
  }
  __syncthreads();

#define MACQ_VV(q, A, B) { uintx4 hq = hl4[q];            \
    s0a = fdot2h(A[0], hq[0], s0a); s0b = fdot2h(A[1], hq[1], s0b); \
    s0a = fdot2h(A[2], hq[2], s0a); s0b = fdot2h(A[3], hq[3], s0b); \
    s1a = fdot2h(B[0], hq[0], s1a); s1b = fdot2h(B[1], hq[1], s1b); \
    s1a = fdot2h(B[2], hq[2], s1a); s1b = fdot2h(B[3], hq[3], s1b); }
#define MACQ_VL(q, A, lq) { uintx4 hq = hl4[q]; uintx4 wb = wl4[(lq) * 512 + j]; \
    s0a = fdot2h(A[0], hq[0], s0a); s0b = fdot2h(A[1], hq[1], s0b); \
    s0a = fdot2h(A[2], hq[2], s0a); s0b = fdot2h(A[3], hq[3], s0b); \
    s1a = fdot2h(wb[0], hq[0], s1a); s1b = fdot2h(wb[1], hq[1], s1b); \
    s1a = fdot2h(wb[2], hq[2], s1a); s1b = fdot2h(wb[3], hq[3], s1b); }

  const float* xgp = xg + (size_t)(k * 64 + b) * 32768;   // 32 steps * 1024 gates
  float xa = xgp[j], xb2 = xgp[512 + j];
#pragma unroll 1
  for (int ct = 0; ct < 32; ++ct) {
    float g0 = xa, g1 = xb2;
    if (ct < 31) { xa = xgp[(ct + 1) * 1024 + j]; xb2 = xgp[(ct + 1) * 1024 + 512 + j]; }

    float s0a = 0.f, s0b = 0.f, s1a = 0.f, s1b = 0.f;
    MACQ_VV(0,  W0,  W32)  MACQ_VV(1,  W1,  W33)  MACQ_VV(2,  W2,  W34)
    MACQ_VV(3,  W3,  W35)  MACQ_VV(4,  W4,  W36)  MACQ_VV(5,  W5,  W37)
    MACQ_VV(6,  W6,  W38)  MACQ_VV(7,  W7,  W39)  MACQ_VV(8,  W8,  W40)
    MACQ_VV(9,  W9,  W41)  MACQ_VV(10, W10, W42)  MACQ_VV(11, W11, W43)
    MACQ_VV(12, W12, W44)  MACQ_VV(13, W13, W45)
    MACQ_VL(14, W14, 0)    MACQ_VL(15, W15, 1)    MACQ_VL(16, W16, 2)
    MACQ_VL(17, W17, 3)    MACQ_VL(18, W18, 4)    MACQ_VL(19, W19, 5)
    MACQ_VL(20, W20, 6)    MACQ_VL(21, W21, 7)    MACQ_VL(22, W22, 8)
    MACQ_VL(23, W23, 9)    MACQ_VL(24, W24, 10)   MACQ_VL(25, W25, 11)
    MACQ_VL(26, W26, 12)   MACQ_VL(27, W27, 13)   MACQ_VL(28, W28, 14)
    MACQ_VL(29, W29, 15)   MACQ_VL(30, W30, 16)   MACQ_VL(31, W31, 17)

    gl[j] = g0 + (s0a + s0b);
    gl[512 + j] = g1 + (s1a + s1b);
    __syncthreads();
    if (j < 256) {
      float iv = gl[j], fv = gl[256 + j], gv = gl[512 + j], ov = gl[768 + j];
      float cn = sigm(fv) * cst + sigm(iv) * tanhf(gv);
      float hn = sigm(ov) * tanhf(cn);
      cst = cn; hlast = hn;
      out[((size_t)(t0 + ct) * 64 + b) * 1024 + k * 256 + j] = hn;
      ((_Float16*)lds)[j] = (_Float16)hn;
    }
    __syncthreads();
  }
#undef MACQ_VV
#undef MACQ_VL
  if (j < 256) {
    int si = (k * 64 + b) * 256 + j;
    state[si] = hlast;
    state[65536 + si] = cst;
    if (last) {
      int gi = b * 1024 + k * 256 + j;
      out[33554432 + gi] = hlast;            // new_h
      out[33554432 + 65536 + gi] = cst;      // new_c
    }
  }
}

extern "C" void kernel_launch(void* const* d_in, const int* in_sizes, int n_in,
                              void* d_out, int out_size, void* d_ws, size_t ws_size,
                              hipStream_t stream) {
  const float* x   = (const float*)d_in[0];
  const float* h0  = (const float*)d_in[1];
  const float* c0  = (const float*)d_in[2];
  const float* Wih = (const float*)d_in[3];
  const float* Whh = (const float*)d_in[4];
  const float* bih = (const float*)d_in[5];
  const float* bhh = (const float*)d_in[6];
  float* out = (float*)d_out;
  char* ws = (char*)d_ws;

  // total ws usage: 36,175,872 B
  float*  xg    = (float*)ws;                   // 4*64*32*1024 f32 = 33,554,432 B
  uint32* whh16 = (uint32*)(ws + 33554432L);    //  2,097,152 B (f16 pairs)
  float*  state = (float*)(ws + 35651584L);     //    524,288 B

  hipFuncSetAttribute((const void*)lstm32, hipFuncAttributeMaxDynamicSharedMemorySize, 152064);

  pack_whh<<<2048, 256, 0, stream>>>(Whh, whh16);
  for (int c = 0; c < 16; ++c) {
    int t0 = c * 32;
    xgemm_f32<<<2048, 256, 0, stream>>>(x, Wih, bih, bhh, xg, t0);
    lstm32<<<256, 512, 152064, stream>>>(xg, whh16, h0, c0, out, state, t0, (c == 15) ? 1 : 0);
  }
}

// Round 7
// 1521.088 us; speedup vs baseline: 16.7355x; 2.4689x over previous
//
#include <hip/hip_runtime.h>

typedef _Float16 half8   __attribute__((ext_vector_type(8)));
typedef _Float16 half2_t __attribute__((ext_vector_type(2)));
typedef float    floatx4 __attribute__((ext_vector_type(4)));
typedef unsigned int uintx4 __attribute__((ext_vector_type(4)));
typedef unsigned int uint32;

__device__ __forceinline__ float sigm(float v) { return 1.0f / (1.0f + __expf(-v)); }

__device__ __forceinline__ float fdot2h(uint32 w, uint32 h, float c) {
#if __has_builtin(__builtin_amdgcn_fdot2)
  return __builtin_amdgcn_fdot2(__builtin_bit_cast(half2_t, w), __builtin_bit_cast(half2_t, h), c, false);
#else
  half2_t a = __builtin_bit_cast(half2_t, w), b = __builtin_bit_cast(half2_t, h);
  return c + (float)a[0] * (float)b[0] + (float)a[1] * (float)b[1];
#endif
}

__device__ __forceinline__ uint32 pack_rte(float a, float b) {
  half2_t h; h[0] = (_Float16)a; h[1] = (_Float16)b;
  return __builtin_bit_cast(uint32, h);
}

// ---------------- pack W_ih + W_hh: f32 -> f16 pairs (RTE), flat ----------------
__global__ __launch_bounds__(256) void pack_w(const float* __restrict__ wih, const float* __restrict__ whh,
                                              uint32* __restrict__ wihd, uint32* __restrict__ whhd) {
  for (int p = blockIdx.x * 256 + threadIdx.x; p < 1572864; p += 262144) {
    if (p < 1048576) {
      wihd[p] = pack_rte(wih[2 * p], wih[2 * p + 1]);
    } else {
      int q = p - 1048576;
      whhd[q] = pack_rte(whh[2 * q], whh[2 * q + 1]);
    }
  }
}

// ---------------- pack one CT=32 chunk of x slices: xs[k][R=b*32+ct][512] f16 ----------------
// scalar f32 reads (slice start 341 is odd -> no 8/16B alignment exists), coalesced across pc.
__global__ __launch_bounds__(256) void pack_xc(const float* __restrict__ x, uint32* __restrict__ xsd, int t0) {
  for (int p = blockIdx.x * 256 + threadIdx.x; p < 2097152; p += 524288) {
    int k   = p >> 19;
    int R   = (p >> 8) & 2047;   // R = b*32 + ct
    int pc  = p & 255;
    int b = R >> 5, ct = R & 31;
    int sk = (k * 1024) / 6;     // 0,170,341,512
    const float* src = x + ((size_t)(t0 + ct) * 64 + b) * 1024 + sk + pc * 2;
    xsd[p] = pack_rte(src[0], src[1]);
  }
}

// ---------------- phase 1: xg16 = xs @ Wih^T + bias via f16 MFMA ----------------
// per chunk: M=2048 (R: b=R>>5, ct=R&31), N=1024 gates, K=512. 128x128 tile, BK=64, 4 waves.
// LDS pad-72 stride: MFMA-frag reads 2-way max (free), b128 staging writes exactly-8-cycle.
__global__ __launch_bounds__(256) void gemm16(const _Float16* __restrict__ xs,
                                              const _Float16* __restrict__ wih16,
                                              const float* __restrict__ bih,
                                              const float* __restrict__ bhh,
                                              _Float16* __restrict__ xg) {
  __shared__ _Float16 SL[18432];  // A: [0,9216) 128x72, B: [9216,18432) 128x72; epilogue C: [0,16384)
  const int tid = threadIdx.x;
  const int bid = blockIdx.x;
  const int nt = bid & 7, mt = (bid >> 3) & 15, kb = bid >> 7;
  const int l = tid & 63;
  const int wid = tid >> 6;
  const int wm = wid >> 1, wn = wid & 1;
  const int lr = l & 15, lk = l >> 4;

  floatx4 acc[4][4] = {};
  const _Float16* xsk = xs + ((size_t)kb << 20);      // 2048*512
  const _Float16* wk  = wih16 + ((size_t)kb << 19);   // 1024*512

  for (int kt = 0; kt < 8; ++kt) {
    const int K0 = kt * 64;
    half8 av[4], bv[4];
#pragma unroll
    for (int q = 0; q < 4; ++q) {
      int s = q * 256 + tid;
      int row = s >> 3, c8 = s & 7;
      av[q] = *(const half8*)(xsk + (size_t)(mt * 128 + row) * 512 + K0 + c8 * 8);
      bv[q] = *(const half8*)(wk  + (size_t)(nt * 128 + row) * 512 + K0 + c8 * 8);
    }
#pragma unroll
    for (int q = 0; q < 4; ++q) {
      int s = q * 256 + tid;
      int row = s >> 3, c8 = s & 7;
      *(half8*)&SL[row * 72 + c8 * 8]        = av[q];
      *(half8*)&SL[9216 + row * 72 + c8 * 8] = bv[q];
    }
    __syncthreads();
#pragma unroll
    for (int ks = 0; ks < 2; ++ks) {
      half8 af[4], bf[4];
#pragma unroll
      for (int fm = 0; fm < 4; ++fm)
        af[fm] = *(const half8*)&SL[(wm * 64 + fm * 16 + lr) * 72 + (ks * 4 + lk) * 8];
#pragma unroll
      for (int fn = 0; fn < 4; ++fn)
        bf[fn] = *(const half8*)&SL[9216 + (wn * 64 + fn * 16 + lr) * 72 + (ks * 4 + lk) * 8];
#pragma unroll
      for (int fm = 0; fm < 4; ++fm)
#pragma unroll
        for (int fn = 0; fn < 4; ++fn)
          acc[fm][fn] = __builtin_amdgcn_mfma_f32_16x16x32_f16(af[fm], bf[fn], acc[fm][fn], 0, 0, 0);
    }
    __syncthreads();
  }
  // epilogue: bias add, cvt f16, LDS transpose, coalesced b128 stores
  float bias[4];
#pragma unroll
  for (int fn = 0; fn < 4; ++fn) {
    int g = nt * 128 + wn * 64 + fn * 16 + lr;
    bias[fn] = bih[kb * 1024 + g] + bhh[kb * 1024 + g];
  }
#pragma unroll
  for (int fm = 0; fm < 4; ++fm)
#pragma unroll
    for (int fn = 0; fn < 4; ++fn) {
      int colb = wn * 64 + fn * 16 + lr;          // gate col within tile (C/D: col = lane&15)
#pragma unroll
      for (int r = 0; r < 4; ++r) {
        int rowb = wm * 64 + fm * 16 + lk * 4 + r; // A row within tile (row = (lane>>4)*4 + r)
        SL[rowb * 128 + colb] = (_Float16)(acc[fm][fn][r] + bias[fn]);
      }
    }
  __syncthreads();
#pragma unroll
  for (int q = 0; q < 8; ++q) {
    int s = q * 256 + tid;
    int row = s >> 4, c16 = s & 15;
    int R = mt * 128 + row;                        // b = R>>5, ct = R&31
    size_t off = ((size_t)(kb * 64 + (R >> 5)) * 32 + (R & 31)) * 1024 + nt * 128 + c16 * 8;
    *(uintx4*)(xg + off) = *(const uintx4*)&SL[row * 128 + c16 * 8];
  }
}

// ---------------- phase 2: 256 independent chains, 1 block/(k,b), CT=32 steps ----------------
// (unchanged from round 6 except xg is now f16) — named-SSA weights, fdot2, no scratch.
__global__ __launch_bounds__(512, 2) void lstm32(const _Float16* __restrict__ xg,
                                                 const uint32* __restrict__ whh16,
                                                 const float* __restrict__ h0,
                                                 const float* __restrict__ c0,
                                                 float* __restrict__ out,
                                                 float* __restrict__ state, int t0, int last) {
  extern __shared__ uint32 lds[];
  const uintx4* hl4 = (const uintx4*)lds;       // 32 quads = 128 dw (h pairs)
  float*  gl  = (float*)(lds + 128);            // 1024 f32
  uintx4* wl4 = (uintx4*)(lds + 1152);          // 18*512 quads
  const int j = threadIdx.x;
  const int k = blockIdx.x >> 6, b = blockIdx.x & 63;

  const uintx4* w0q = (const uintx4*)(whh16 + ((size_t)(k * 1024 + j) << 7));
  const uintx4* w1q = (const uintx4*)(whh16 + ((size_t)(k * 1024 + 512 + j) << 7));
  uintx4 W0  = w0q[0],  W1  = w0q[1],  W2  = w0q[2],  W3  = w0q[3];
  uintx4 W4  = w0q[4],  W5  = w0q[5],  W6  = w0q[6],  W7  = w0q[7];
  uintx4 W8  = w0q[8],  W9  = w0q[9],  W10 = w0q[10], W11 = w0q[11];
  uintx4 W12 = w0q[12], W13 = w0q[13], W14 = w0q[14], W15 = w0q[15];
  uintx4 W16 = w0q[16], W17 = w0q[17], W18 = w0q[18], W19 = w0q[19];
  uintx4 W20 = w0q[20], W21 = w0q[21], W22 = w0q[22], W23 = w0q[23];
  uintx4 W24 = w0q[24], W25 = w0q[25], W26 = w0q[26], W27 = w0q[27];
  uintx4 W28 = w0q[28], W29 = w0q[29], W30 = w0q[30], W31 = w0q[31];
  uintx4 W32 = w1q[0],  W33 = w1q[1],  W34 = w1q[2],  W35 = w1q[3];
  uintx4 W36 = w1q[4],  W37 = w1q[5],  W38 = w1q[6],  W39 = w1q[7];
  uintx4 W40 = w1q[8],  W41 = w1q[9],  W42 = w1q[10], W43 = w1q[11];
  uintx4 W44 = w1q[12], W45 = w1q[13];
#pragma unroll
  for (int q = 14; q < 32; ++q) wl4[(q - 14) * 512 + j] = w1q[q];

  float cst = 0.f, hlast = 0.f;
  if (j < 256) {
    int gi = b * 1024 + k * 256 + j;
    int si = (k * 64 + b) * 256 + j;
    float hv, cv;
    if (t0 == 0) { hv = h0[gi]; cv = c0[gi]; }
    else         { hv = state[si]; cv = state[65536 + si]; }
    cst = cv; hlast = hv;
    ((_Float16*)lds)[j] = (_Float16)hv;
  }
  __syncthreads();

#define MACQ_VV(q, A, B) { uintx4 hq = hl4[q];            \
    s0a = fdot2h(A[0], hq[0], s0a); s0b = fdot2h(A[1], hq[1], s0b); \
    s0a = fdot2h(A[2], hq[2], s0a); s0b = fdot2h(A[3], hq[3], s0b); \
    s1a = fdot2h(B[0], hq[0], s1a); s1b = fdot2h(B[1], hq[1], s1b); \
    s1a = fdot2h(B[2], hq[2], s1a); s1b = fdot2h(B[3], hq[3], s1b); }
#define MACQ_VL(q, A, lq) { uintx4 hq = hl4[q]; uintx4 wb = wl4[(lq) * 512 + j]; \
    s0a = fdot2h(A[0], hq[0], s0a); s0b = fdot2h(A[1], hq[1], s0b); \
    s0a = fdot2h(A[2], hq[2], s0a); s0b = fdot2h(A[3], hq[3], s0b); \
    s1a = fdot2h(wb[0], hq[0], s1a); s1b = fdot2h(wb[1], hq[1], s1b); \
    s1a = fdot2h(wb[2], hq[2], s1a); s1b = fdot2h(wb[3], hq[3], s1b); }

  const _Float16* xgp = xg + (size_t)(k * 64 + b) * 32768;   // 32 steps * 1024 gates (f16)
  _Float16 xa = xgp[j], xb2 = xgp[512 + j];
#pragma unroll 1
  for (int ct = 0; ct < 32; ++ct) {
    float g0 = (float)xa, g1 = (float)xb2;
    if (ct < 31) { xa = xgp[(ct + 1) * 1024 + j]; xb2 = xgp[(ct + 1) * 1024 + 512 + j]; }

    float s0a = 0.f, s0b = 0.f, s1a = 0.f, s1b = 0.f;
    MACQ_VV(0,  W0,  W32)  MACQ_VV(1,  W1,  W33)  MACQ_VV(2,  W2,  W34)
    MACQ_VV(3,  W3,  W35)  MACQ_VV(4,  W4,  W36)  MACQ_VV(5,  W5,  W37)
    MACQ_VV(6,  W6,  W38)  MACQ_VV(7,  W7,  W39)  MACQ_VV(8,  W8,  W40)
    MACQ_VV(9,  W9,  W41)  MACQ_VV(10, W10, W42)  MACQ_VV(11, W11, W43)
    MACQ_VV(12, W12, W44)  MACQ_VV(13, W13, W45)
    MACQ_VL(14, W14, 0)    MACQ_VL(15, W15, 1)    MACQ_VL(16, W16, 2)
    MACQ_VL(17, W17, 3)    MACQ_VL(18, W18, 4)    MACQ_VL(19, W19, 5)
    MACQ_VL(20, W20, 6)    MACQ_VL(21, W21, 7)    MACQ_VL(22, W22, 8)
    MACQ_VL(23, W23, 9)    MACQ_VL(24, W24, 10)   MACQ_VL(25, W25, 11)
    MACQ_VL(26, W26, 12)   MACQ_VL(27, W27, 13)   MACQ_VL(28, W28, 14)
    MACQ_VL(29, W29, 15)   MACQ_VL(30, W30, 16)   MACQ_VL(31, W31, 17)

    gl[j] = g0 + (s0a + s0b);
    gl[512 + j] = g1 + (s1a + s1b);
    __syncthreads();
    if (j < 256) {
      float iv = gl[j], fv = gl[256 + j], gv = gl[512 + j], ov = gl[768 + j];
      float cn = sigm(fv) * cst + sigm(iv) * tanhf(gv);
      float hn = sigm(ov) * tanhf(cn);
      cst = cn; hlast = hn;
      out[((size_t)(t0 + ct) * 64 + b) * 1024 + k * 256 + j] = hn;
      ((_Float16*)lds)[j] = (_Float16)hn;
    }
    __syncthreads();
  }
#undef MACQ_VV
#undef MACQ_VL
  if (j < 256) {
    int si = (k * 64 + b) * 256 + j;
    state[si] = hlast;
    state[65536 + si] = cst;
    if (last) {
      int gi = b * 1024 + k * 256 + j;
      out[33554432 + gi] = hlast;            // new_h
      out[33554432 + 65536 + gi] = cst;      // new_c
    }
  }
}

extern "C" void kernel_launch(void* const* d_in, const int* in_sizes, int n_in,
                              void* d_out, int out_size, void* d_ws, size_t ws_size,
                              hipStream_t stream) {
  const float* x   = (const float*)d_in[0];
  const float* h0  = (const float*)d_in[1];
  const float* c0  = (const float*)d_in[2];
  const float* Wih = (const float*)d_in[3];
  const float* Whh = (const float*)d_in[4];
  const float* bih = (const float*)d_in[5];
  const float* bhh = (const float*)d_in[6];
  float* out = (float*)d_out;
  char* ws = (char*)d_ws;

  // total ws usage: 31,981,568 B (stays under the known-good 36.2 MB)
  _Float16* xg16  = (_Float16*)ws;                  // 4*64*32*1024 f16 = 16,777,216 B
  _Float16* xs    = (_Float16*)(ws + 16777216L);    // 4*2048*512 f16  =  8,388,608 B
  _Float16* wih16 = (_Float16*)(ws + 25165824L);    //  4,194,304 B
  uint32*   whh16 = (uint32*)(ws + 29360128L);      //  2,097,152 B (f16 pairs)
  float*    state = (float*)(ws + 31457280L);       //    524,288 B

  hipFuncSetAttribute((const void*)lstm32, hipFuncAttributeMaxDynamicSharedMemorySize, 152064);

  pack_w<<<1024, 256, 0, stream>>>(Wih, Whh, (uint32*)wih16, whh16);
  for (int c = 0; c < 16; ++c) {
    int t0 = c * 32;
    pack_xc<<<2048, 256, 0, stream>>>(x, (uint32*)xs, t0);
    gemm16<<<512, 256, 0, stream>>>(xs, wih16, bih, bhh, xg16);
    lstm32<<<256, 512, 152064, stream>>>(xg16, whh16, h0, c0, out, state, t0, (c == 15) ? 1 : 0);
  }
}